// Round 1
// baseline (349.952 us; speedup 1.0000x reference)
//
#include <hip/hip_runtime.h>
#include <cstdint>
#include <cstddef>

typedef unsigned short u16;
typedef short short8 __attribute__((ext_vector_type(8)));
typedef unsigned short u16x8 __attribute__((ext_vector_type(8)));
typedef unsigned short u16x4 __attribute__((ext_vector_type(4)));
typedef float f32x4 __attribute__((ext_vector_type(4)));

#define DEVI __device__ __forceinline__

#if defined(__has_builtin)
#if __has_builtin(__builtin_amdgcn_global_load_lds)
#define USE_GLD 1
#endif
#endif

DEVI float bf2f(u16 u) { return __uint_as_float(((unsigned)u) << 16); }
DEVI u16 f2bf(float f) {
  unsigned u = __float_as_uint(f);
  u += 0x7FFFu + ((u >> 16) & 1u);  // RNE
  return (u16)(u >> 16);
}

DEVI void stage16(const u16* __restrict__ g, u16* lds_base, int lane) {
#ifdef USE_GLD
  __builtin_amdgcn_global_load_lds(
      (const __attribute__((address_space(1))) unsigned int*)g,
      (__attribute__((address_space(3))) unsigned int*)lds_base, 16, 0, 0);
#else
  *(u16x8*)(lds_base + lane * 8) = *(const u16x8*)g;
#endif
}

// ---------------- CSR build ----------------
__global__ void build_deg(const int* __restrict__ dst, int* __restrict__ deg, int E) {
  int e = blockIdx.x * 256 + threadIdx.x;
  if (e < E) atomicAdd(&deg[dst[e]], 1);
}

__global__ __launch_bounds__(256) void scan1(const int* __restrict__ deg,
                                             int* __restrict__ pref,
                                             int* __restrict__ bsum, int Nn) {
  __shared__ int wsum[4];
  int i = blockIdx.x * 256 + threadIdx.x;
  int lane = threadIdx.x & 63, w = threadIdx.x >> 6;
  int v = (i < Nn) ? deg[i] : 0;
  int s = v;
  for (int off = 1; off < 64; off <<= 1) {
    int t = __shfl_up(s, off, 64);
    if (lane >= off) s += t;
  }
  if (lane == 63) wsum[w] = s;
  __syncthreads();
  int add = 0;
  for (int k = 0; k < w; ++k) add += wsum[k];
  int incl = s + add;
  if (i < Nn) pref[i] = incl - v;
  if (threadIdx.x == 255) bsum[blockIdx.x] = incl;
}

__global__ __launch_bounds__(256) void scan2(int* __restrict__ bsum,
                                             int* __restrict__ row_ofs,
                                             int nb, int Nn) {
  __shared__ int wsum[4];
  int t = threadIdx.x;
  int lane = t & 63, w = t >> 6;
  int v = (t < nb) ? bsum[t] : 0;
  int s = v;
  for (int off = 1; off < 64; off <<= 1) {
    int u = __shfl_up(s, off, 64);
    if (lane >= off) s += u;
  }
  if (lane == 63) wsum[w] = s;
  __syncthreads();
  int add = 0;
  for (int k = 0; k < w; ++k) add += wsum[k];
  int incl = s + add;
  if (t < nb) bsum[t] = incl - v;
  if (t == 255) row_ofs[Nn] = incl;
}

__global__ __launch_bounds__(256) void scan3(const int* __restrict__ pref,
                                             const int* __restrict__ bsum,
                                             int* __restrict__ row_ofs,
                                             int* __restrict__ cursor, int Nn) {
  int i = blockIdx.x * 256 + threadIdx.x;
  if (i < Nn) {
    int r = pref[i] + bsum[blockIdx.x];
    row_ofs[i] = r;
    cursor[i] = r;
  }
}

__global__ void csr_fill(const int* __restrict__ src, const int* __restrict__ dst,
                         int* __restrict__ cursor, int* __restrict__ col, int E) {
  int e = blockIdx.x * 256 + threadIdx.x;
  if (e < E) {
    int p = atomicAdd(&cursor[dst[e]], 1);
    col[p] = src[e];
  }
}

// ------------- merged weight pack -------------
__global__ __launch_bounds__(256) void pack_all(
    const float* __restrict__ W1, const float* __restrict__ W2,
    const float* __restrict__ Wh1, u16* __restrict__ B1t,
    u16* __restrict__ B2t, u16* __restrict__ Bht) {
  int b = blockIdx.x;
  if (b < 1024) {
    int c = b >> 1;
    int k = (b & 1) * 256 + threadIdx.x;
    if (k < 384) {
      float v = (c < 256) ? W1[(size_t)k * 256 + c]
                          : W1[(size_t)(384 + k) * 256 + (c - 256)];
      B1t[(size_t)c * 384 + k] = f2bf(v);
    }
  } else if (b < 1536) {
    int c = b - 1024;
    int k = threadIdx.x;
    float v = (c < 256) ? W2[(size_t)k * 256 + c]
                        : W2[(size_t)(256 + k) * 256 + (c - 256)];
    B2t[(size_t)c * 256 + k] = f2bf(v);
  } else {
    int c = b - 1536;
    int k = threadIdx.x;
    Bht[(size_t)c * 256 + k] = f2bf(Wh1[(size_t)k * 128 + c]);
  }
}

// ------------- merged bias -------------
__global__ __launch_bounds__(384) void bias_all(
    const float* __restrict__ W1, const float* __restrict__ b1,
    const float* __restrict__ W2, const float* __restrict__ b2,
    const float* __restrict__ Wh1, const float* __restrict__ bh1,
    const float* __restrict__ q, float* __restrict__ cq1,
    float* __restrict__ cq2, float* __restrict__ cqh) {
  __shared__ float part[6];
  int b = blockIdx.x;
  const float* W; const float* bb; float* o; int ld, roff, c;
  if (b < 256)      { W = W1;  bb = b1;  o = cq1; ld = 256; roff = 768; c = b; }
  else if (b < 512) { W = W2;  bb = b2;  o = cq2; ld = 256; roff = 512; c = b - 256; }
  else              { W = Wh1; bb = bh1; o = cqh; ld = 128; roff = 256; c = b - 512; }
  int t = threadIdx.x;
  float p = q[t] * W[(size_t)(roff + t) * ld + c];
  for (int off = 32; off > 0; off >>= 1) p += __shfl_down(p, off, 64);
  if ((t & 63) == 0) part[t >> 6] = p;
  __syncthreads();
  if (t == 0) {
    float acc = bb[c];
    for (int w = 0; w < 6; ++w) acc += part[w];
    o[c] = acc;
  }
}

// ================= wide GEMM v13: 128x256 tile, 512 threads (8 waves, 2x4),
// double-buffered LDS, T3-minimum schedule: stage tile t+1 BEFORE computing
// tile t, drain (syncthreads vmcnt0) AFTER the MFMAs — stage overlaps compute.
// Fragment layout / XOR quad-swizzle / epilogue identical to the proven r12
// kernel; only geometry and schedule changed.
#define G2_ACH 4096            // A 32-K-chunk elems (128*32)
#define G2_ASZ 8192            // A per-tile elems (128*64)
#define G2_BCH 8192            // B 32-K-chunk elems (256*32)
#define G2_BSZ 16384           // B per-tile elems (256*64)
#define G2_SMEM (2 * G2_ASZ + 2 * G2_BSZ)  // 49152 elems = 96 KB
#define G2_ES 264              // epilogue LDS row stride (pad 8)

#define G2_B_SETUP()                                                           \
  const u16* pbB[2];                                                           \
  _Pragma("unroll") for (int p = 0; p < 2; ++p) {                              \
    int L = p * 512 + tid;                                                     \
    int c = L >> 2, qs = L & 3;                                                \
    int g = qs ^ ((c >> 1) & 3);                                               \
    pbB[p] = Bt + (size_t)(cb * 256 + c) * K + g * 8;                          \
  }

#define G2_B_STAGE(LBDST)                                                      \
  _Pragma("unroll") for (int p = 0; p < 2; ++p) {                              \
    u16* d = (LBDST) + (size_t)(p * 512 + wave * 64) * 8;                      \
    stage16(pbB[p], d, lane);                                                  \
    stage16(pbB[p] + 32, d + G2_BCH, lane);                                    \
    pbB[p] += 64;                                                              \
  }

#define G2_COMPUTE(LA, LB)                                                     \
  _Pragma("unroll") for (int cc = 0; cc < 2; ++cc) {                           \
    short8 bfr[4];                                                             \
    _Pragma("unroll") for (int nt = 0; nt < 4; ++nt)                           \
      bfr[nt] = *(const short8*)&(LB)[cc * G2_BCH +                            \
                  ((wc * 64 + nt * 16 + m) * 4 + csel) * 8];                   \
    _Pragma("unroll") for (int mt = 0; mt < 4; ++mt) {                         \
      short8 af = *(const short8*)&(LA)[cc * G2_ACH +                          \
                  ((wr * 64 + mt * 16 + m) * 4 + csel) * 8];                   \
      _Pragma("unroll") for (int nt = 0; nt < 4; ++nt)                         \
        acc[mt][nt] = __builtin_amdgcn_mfma_f32_16x16x32_bf16(                 \
            af, bfr[nt], acc[mt][nt], 0, 0, 0);                                \
    }                                                                          \
  }

#define G2_EPILOGUE()                                                          \
  {                                                                            \
    u16* et = smem;                                                            \
    _Pragma("unroll") for (int mt = 0; mt < 4; ++mt)                           \
    _Pragma("unroll") for (int nt = 0; nt < 4; ++nt) {                         \
      int colL = wc * 64 + nt * 16 + m;                                        \
      int gcol = cb * 256 + colL;                                              \
      float bb = (gcol < bias_len) ? bias[gcol] : 0.0f;                        \
      _Pragma("unroll") for (int r = 0; r < 4; ++r) {                          \
        float v = acc[mt][nt][r] + bb;                                         \
        if (relu) v = fmaxf(v, 0.0f);                                          \
        et[(wr * 64 + mt * 16 + quad * 4 + r) * G2_ES + colL] = f2bf(v);       \
      }                                                                        \
    }                                                                          \
    __syncthreads();                                                           \
    _Pragma("unroll") for (int rep = 0; rep < 8; ++rep) {                      \
      int idx = rep * 512 + tid;                                               \
      int row = idx >> 5, ch = idx & 31;                                       \
      int grow = row0 + row;                                                   \
      if (grow < M)                                                            \
        *(u16x8*)&C[(size_t)grow * 512 + cb * 256 + ch * 8] =                  \
            *(const u16x8*)&et[row * G2_ES + ch * 8];                          \
    }                                                                          \
  }

__global__ __launch_bounds__(512, 2) void gemm256_f32a(
    const float* __restrict__ A, const u16* __restrict__ Bt,
    u16* __restrict__ C, const float* __restrict__ bias,
    int M, int K, int bias_len, int relu) {
  __shared__ __align__(16) u16 smem[G2_SMEM];
  u16* a0 = smem;
  u16* a1 = smem + G2_ASZ;
  u16* b0 = smem + 2 * G2_ASZ;
  u16* b1 = b0 + G2_BSZ;

  const int tid = threadIdx.x;
  const int lane = tid & 63;
  const int wave = tid >> 6;     // 0..7
  const int wr = wave >> 2;      // row half
  const int wc = wave & 3;       // col quarter
  const int cb = blockIdx.x & 1; // 256-col block
  const int row0 = (blockIdx.x >> 1) * 128;
  const int m = lane & 15;
  const int quad = lane >> 4;
  const int csel = quad ^ ((m >> 1) & 3);

  const int rA = tid >> 2;       // 0..127
  const int qA = tid & 3;
  const int sA = rA * 4 + (qA ^ ((rA >> 1) & 3));
  int ga = row0 + rA; if (ga >= M) ga = M - 1;
  const float* pa = A + (size_t)ga * K + qA * 8;

  G2_B_SETUP()

  f32x4 acc[4][4] = {};

  // A[0] into regs
  f32x4 v0a = *(const f32x4*)pa, v0b = *(const f32x4*)(pa + 4);
  f32x4 v1a = *(const f32x4*)(pa + 32), v1b = *(const f32x4*)(pa + 36);
  pa += 64;

  // prologue: stage tile 0, write A[0], prefetch A[1]
  G2_B_STAGE(b0)
  {
    u16x8 h0, h1;
#pragma unroll
    for (int j = 0; j < 4; ++j) {
      h0[j] = f2bf(v0a[j]); h0[j + 4] = f2bf(v0b[j]);
      h1[j] = f2bf(v1a[j]); h1[j + 4] = f2bf(v1b[j]);
    }
    *(u16x8*)&a0[sA * 8] = h0;
    *(u16x8*)&a0[G2_ACH + sA * 8] = h1;
  }
  {
    const float* pn = (64 < K) ? pa : A;
    v0a = *(const f32x4*)pn; v0b = *(const f32x4*)(pn + 4);
    v1a = *(const f32x4*)(pn + 32); v1b = *(const f32x4*)(pn + 36);
    pa += 64;
  }
  __syncthreads();

  const int NT = K >> 6;
  for (int t = 0; t < NT; ++t) {
    u16* la  = (t & 1) ? a1 : a0;
    u16* lb  = (t & 1) ? b1 : b0;
    u16* lan = (t & 1) ? a0 : a1;
    u16* lbn = (t & 1) ? b0 : b1;
    if (t + 1 < NT) {
      G2_B_STAGE(lbn)
      u16x8 h0, h1;
#pragma unroll
      for (int j = 0; j < 4; ++j) {
        h0[j] = f2bf(v0a[j]); h0[j + 4] = f2bf(v0b[j]);
        h1[j] = f2bf(v1a[j]); h1[j + 4] = f2bf(v1b[j]);
      }
      *(u16x8*)&lan[sA * 8] = h0;
      *(u16x8*)&lan[G2_ACH + sA * 8] = h1;
      const float* pn = (t + 2 < NT) ? pa : A;
      v0a = *(const f32x4*)pn; v0b = *(const f32x4*)(pn + 4);
      v1a = *(const f32x4*)(pn + 32); v1b = *(const f32x4*)(pn + 36);
      pa += 64;
    }
    G2_COMPUTE(la, lb)
    __syncthreads();
  }

  G2_EPILOGUE()
}

__global__ __launch_bounds__(512, 2) void gemm256_bf16a(
    const u16* __restrict__ A, const u16* __restrict__ Bt,
    u16* __restrict__ C, const float* __restrict__ bias,
    int M, int K, int bias_len, int relu) {
  __shared__ __align__(16) u16 smem[G2_SMEM];
  u16* a0 = smem;
  u16* a1 = smem + G2_ASZ;
  u16* b0 = smem + 2 * G2_ASZ;
  u16* b1 = b0 + G2_BSZ;

  const int tid = threadIdx.x;
  const int lane = tid & 63;
  const int wave = tid >> 6;
  const int wr = wave >> 2;
  const int wc = wave & 3;
  const int cb = blockIdx.x & 1;
  const int row0 = (blockIdx.x >> 1) * 128;
  const int m = lane & 15;
  const int quad = lane >> 4;
  const int csel = quad ^ ((m >> 1) & 3);

  const int rA = tid >> 2;
  const int qA = tid & 3;
  const int sA = rA * 4 + (qA ^ ((rA >> 1) & 3));
  int ga = row0 + rA; if (ga >= M) ga = M - 1;
  const u16* pa = A + (size_t)ga * K + qA * 8;

  G2_B_SETUP()

  f32x4 acc[4][4] = {};

  u16x8 va0 = *(const u16x8*)pa;
  u16x8 va1 = *(const u16x8*)(pa + 32);
  pa += 64;

  G2_B_STAGE(b0)
  *(u16x8*)&a0[sA * 8] = va0;
  *(u16x8*)&a0[G2_ACH + sA * 8] = va1;
  {
    const u16* pn = (64 < K) ? pa : A;
    va0 = *(const u16x8*)pn;
    va1 = *(const u16x8*)(pn + 32);
    pa += 64;
  }
  __syncthreads();

  const int NT = K >> 6;
  for (int t = 0; t < NT; ++t) {
    u16* la  = (t & 1) ? a1 : a0;
    u16* lb  = (t & 1) ? b1 : b0;
    u16* lan = (t & 1) ? a0 : a1;
    u16* lbn = (t & 1) ? b0 : b1;
    if (t + 1 < NT) {
      G2_B_STAGE(lbn)
      *(u16x8*)&lan[sA * 8] = va0;
      *(u16x8*)&lan[G2_ACH + sA * 8] = va1;
      const u16* pn = (t + 2 < NT) ? pa : A;
      va0 = *(const u16x8*)pn;
      va1 = *(const u16x8*)(pn + 32);
      pa += 64;
    }
    G2_COMPUTE(la, lb)
    __syncthreads();
  }

  G2_EPILOGUE()
}

// ========== fused head (round-12 proven): out = relu(h2@Wh1h+cqh).Wh2+bh2 ====
#define BM 128
#define BK 32

__global__ __launch_bounds__(256) void gemm_head(
    const u16* __restrict__ A, const u16* __restrict__ Bt,
    const float* __restrict__ cqh, const float* __restrict__ Wh2,
    const float* __restrict__ bh2, float* __restrict__ out, int M, int K) {
  __shared__ __align__(16) u16 lds_a[BM * BK];
  __shared__ __align__(16) u16 lds_b[BM * BK];
  __shared__ float red[128][2];

  const int tid = threadIdx.x;
  const int lane = tid & 63;
  const int wave = tid >> 6;
  const int wm = wave & 1, wn = wave >> 1;
  const int row0 = blockIdx.x * BM;
  const int m = lane & 15;
  const int quad = lane >> 4;
  const int csel = quad ^ ((m >> 1) & 3);

  const int r0 = tid >> 2, r1 = 64 + r0;
  const int cs = tid & 3;
  const int s0 = r0 * 4 + (cs ^ ((r0 >> 1) & 3));
  const int s1 = r1 * 4 + (cs ^ ((r1 >> 1) & 3));
  const int cb0 = cs ^ ((r0 >> 1) & 3);
  const int cb1 = cs ^ ((r1 >> 1) & 3);
  int ga0 = row0 + r0; if (ga0 >= M) ga0 = M - 1;
  int ga1 = row0 + r1; if (ga1 >= M) ga1 = M - 1;
  const u16* pa0 = A + (size_t)ga0 * K + cs * 8;
  const u16* pa1 = A + (size_t)ga1 * K + cs * 8;
  const u16* pb0 = Bt + (size_t)r0 * K + cb0 * 8;
  const u16* pb1 = Bt + (size_t)r1 * K + cb1 * 8;
  u16* lb0 = lds_b + (size_t)(wave * 64) * 8;
  u16* lb1 = lds_b + (size_t)(256 + wave * 64) * 8;

  f32x4 acc[4][4] = {};

  u16x8 va0 = *(const u16x8*)pa0; pa0 += BK;
  u16x8 va1 = *(const u16x8*)pa1; pa1 += BK;

  for (int k0 = 0; k0 < K; k0 += BK) {
    __syncthreads();
    stage16(pb0, lb0, lane); pb0 += BK;
    stage16(pb1, lb1, lane); pb1 += BK;
    *(u16x8*)&lds_a[s0 * 8] = va0;
    *(u16x8*)&lds_a[s1 * 8] = va1;
    const u16* n0 = (k0 + BK < K) ? pa0 : A;
    const u16* n1 = (k0 + BK < K) ? pa1 : A;
    u16x8 w0 = *(const u16x8*)n0;
    u16x8 w1 = *(const u16x8*)n1;
    pa0 += BK; pa1 += BK;
    __syncthreads();

    short8 af[4], bfv[4];
#pragma unroll
    for (int mt = 0; mt < 4; ++mt)
      af[mt] = *(const short8*)&lds_a[((wm * 64 + mt * 16 + m) * 4 + csel) * 8];
#pragma unroll
    for (int nt = 0; nt < 4; ++nt)
      bfv[nt] = *(const short8*)&lds_b[((wn * 64 + nt * 16 + m) * 4 + csel) * 8];
#pragma unroll
    for (int mt = 0; mt < 4; ++mt)
#pragma unroll
      for (int nt = 0; nt < 4; ++nt)
        acc[mt][nt] = __builtin_amdgcn_mfma_f32_16x16x32_bf16(
            af[mt], bfv[nt], acc[mt][nt], 0, 0, 0);
    va0 = w0; va1 = w1;
  }

  float part[4][4];
#pragma unroll
  for (int mt = 0; mt < 4; ++mt)
#pragma unroll
    for (int r = 0; r < 4; ++r) part[mt][r] = 0.0f;
#pragma unroll
  for (int nt = 0; nt < 4; ++nt) {
    int col = wn * 64 + nt * 16 + m;
    float bb = cqh[col];
    float w2 = Wh2[col];
#pragma unroll
    for (int mt = 0; mt < 4; ++mt)
#pragma unroll
      for (int r = 0; r < 4; ++r)
        part[mt][r] += fmaxf(acc[mt][nt][r] + bb, 0.0f) * w2;
  }
#pragma unroll
  for (int off = 8; off > 0; off >>= 1)
#pragma unroll
    for (int mt = 0; mt < 4; ++mt)
#pragma unroll
      for (int r = 0; r < 4; ++r)
        part[mt][r] += __shfl_xor(part[mt][r], off, 64);
  if (m == 0) {
#pragma unroll
    for (int mt = 0; mt < 4; ++mt)
#pragma unroll
      for (int r = 0; r < 4; ++r)
        red[wm * 64 + mt * 16 + quad * 4 + r][wn] = part[mt][r];
  }
  __syncthreads();
  if (tid < 128) {
    int grow = row0 + tid;
    if (grow < M) out[grow] = red[tid][0] + red[tid][1] + bh2[0];
  }
}

// ---------------- aggregation: H[i] = relu(u_i + (y_i + sum_j y_j)/(deg+1))
__global__ __launch_bounds__(256) void aggregate(
    const u16* __restrict__ C, const int* __restrict__ row_ofs,
    const int* __restrict__ col_idx, u16* __restrict__ H, int Nn) {
  int node = blockIdx.x * 8 + (threadIdx.x >> 5);
  if (node >= Nn) return;
  int l = threadIdx.x & 31;
  int s = row_ofs[node], e = row_ofs[node + 1];
  float inv = 1.0f / (float)(e - s + 1);
  const u16* crow = C + (size_t)node * 512;
  u16x8 y0 = *(const u16x8*)(crow + 256 + l * 8);
  float a[8];
#pragma unroll
  for (int j = 0; j < 8; ++j) a[j] = bf2f(y0[j]);
  int t = s;
  for (; t + 4 <= e; t += 4) {
    int j0 = col_idx[t], j1 = col_idx[t + 1], j2 = col_idx[t + 2], j3 = col_idx[t + 3];
    u16x8 v0 = *(const u16x8*)(C + (size_t)j0 * 512 + 256 + l * 8);
    u16x8 v1 = *(const u16x8*)(C + (size_t)j1 * 512 + 256 + l * 8);
    u16x8 v2 = *(const u16x8*)(C + (size_t)j2 * 512 + 256 + l * 8);
    u16x8 v3 = *(const u16x8*)(C + (size_t)j3 * 512 + 256 + l * 8);
#pragma unroll
    for (int j = 0; j < 8; ++j)
      a[j] += (bf2f(v0[j]) + bf2f(v1[j])) + (bf2f(v2[j]) + bf2f(v3[j]));
  }
  for (; t < e; ++t) {
    int jj = col_idx[t];
    u16x8 vj = *(const u16x8*)(C + (size_t)jj * 512 + 256 + l * 8);
#pragma unroll
    for (int j = 0; j < 8; ++j) a[j] += bf2f(vj[j]);
  }
  u16x8 u = *(const u16x8*)(crow + l * 8);
  u16x8 o;
#pragma unroll
  for (int j = 0; j < 8; ++j)
    o[j] = f2bf(fmaxf(bf2f(u[j]) + a[j] * inv, 0.0f));
  *(u16x8*)(H + (size_t)node * 256 + l * 8) = o;
}

extern "C" void kernel_launch(void* const* d_in, const int* in_sizes, int n_in,
                              void* d_out, int out_size, void* d_ws, size_t ws_size,
                              hipStream_t stream) {
  const float* x   = (const float*)d_in[0];
  const int*   ei  = (const int*)d_in[1];
  const float* q   = (const float*)d_in[2];
  const float* W1  = (const float*)d_in[3];
  const float* b1  = (const float*)d_in[4];
  const float* W2  = (const float*)d_in[5];
  const float* b2  = (const float*)d_in[6];
  const float* Wh1 = (const float*)d_in[7];
  const float* bh1 = (const float*)d_in[8];
  const float* Wh2 = (const float*)d_in[9];
  const float* bh2 = (const float*)d_in[10];

  const int N = in_sizes[0] / 384;
  const int E = in_sizes[1] / 2;
  const int Npad = ((N + 127) / 128) * 128;
  const int* esrc = ei;
  const int* edst = ei + E;

  size_t off = 0;
  auto alloc = [&](size_t bytes) -> void* {
    void* p = (char*)d_ws + off;
    off += (bytes + 255) & ~(size_t)255;
    return p;
  };
  int* deg     = (int*)alloc((size_t)N * 4);
  int* row_ofs = (int*)alloc((size_t)(N + 1) * 4);
  int* cursor  = (int*)alloc((size_t)N * 4);
  int* colidx  = (int*)alloc((size_t)E * 4);
  int* pref    = (int*)alloc((size_t)N * 4);
  int* bsum    = (int*)alloc(256 * 4);
  u16* B1t = (u16*)alloc((size_t)512 * 384 * 2);
  u16* B2t = (u16*)alloc((size_t)512 * 256 * 2);
  u16* Bht = (u16*)alloc((size_t)128 * 256 * 2);
  float* cq1 = (float*)alloc(256 * 4);
  float* cq2 = (float*)alloc(256 * 4);
  float* cqh = (float*)alloc(128 * 4);
  u16* Cbuf = (u16*)alloc((size_t)Npad * 512 * 2);
  u16* Hbuf = (u16*)alloc((size_t)Npad * 256 * 2);

  (void)hipMemsetAsync(deg, 0, (size_t)N * 4, stream);
  int eb = (E + 255) / 256;
  int nb = (N + 255) / 256;
  build_deg<<<eb, 256, 0, stream>>>(edst, deg, E);
  scan1<<<nb, 256, 0, stream>>>(deg, pref, bsum, N);
  scan2<<<1, 256, 0, stream>>>(bsum, row_ofs, nb, N);
  scan3<<<nb, 256, 0, stream>>>(pref, bsum, row_ofs, cursor, N);
  csr_fill<<<eb, 256, 0, stream>>>(esrc, edst, cursor, colidx, E);

  pack_all<<<1664, 256, 0, stream>>>(W1, W2, Wh1, B1t, B2t, Bht);
  bias_all<<<640, 384, 0, stream>>>(W1, b1, W2, b2, Wh1, bh1, q, cq1, cq2, cqh);

  int gb2 = ((N + 127) / 128) * 2;
  int mb = Npad / 128;
  int nb8 = (N + 7) / 8;
  // layer 1
  gemm256_f32a<<<gb2, 512, 0, stream>>>(x, B1t, Cbuf, cq1, N, 384, 256, 0);
  aggregate<<<nb8, 256, 0, stream>>>(Cbuf, row_ofs, colidx, Hbuf, N);
  // layer 2
  gemm256_bf16a<<<gb2, 512, 0, stream>>>(Hbuf, B2t, Cbuf, cq2, N, 256, 256, 0);
  aggregate<<<nb8, 256, 0, stream>>>(Cbuf, row_ofs, colidx, Hbuf, N);
  // fused head
  gemm_head<<<mb, 256, 0, stream>>>(Hbuf, Bht, cqh, Wh2, bh2, (float*)d_out, N, 256);
}

// Round 2
// 348.211 us; speedup vs baseline: 1.0050x; 1.0050x over previous
//
#include <hip/hip_runtime.h>
#include <cstdint>
#include <cstddef>

typedef unsigned short u16;
typedef short short8 __attribute__((ext_vector_type(8)));
typedef unsigned short u16x8 __attribute__((ext_vector_type(8)));
typedef unsigned short u16x4 __attribute__((ext_vector_type(4)));
typedef float f32x4 __attribute__((ext_vector_type(4)));

#define DEVI __device__ __forceinline__

#if defined(__has_builtin)
#if __has_builtin(__builtin_amdgcn_global_load_lds)
#define USE_GLD 1
#endif
#endif

DEVI float bf2f(u16 u) { return __uint_as_float(((unsigned)u) << 16); }
DEVI u16 f2bf(float f) {
  unsigned u = __float_as_uint(f);
  u += 0x7FFFu + ((u >> 16) & 1u);  // RNE
  return (u16)(u >> 16);
}

DEVI void stage16(const u16* __restrict__ g, u16* lds_base, int lane) {
#ifdef USE_GLD
  __builtin_amdgcn_global_load_lds(
      (const __attribute__((address_space(1))) unsigned int*)g,
      (__attribute__((address_space(3))) unsigned int*)lds_base, 16, 0, 0);
#else
  *(u16x8*)(lds_base + lane * 8) = *(const u16x8*)g;
#endif
}

// ---------------- CSR build ----------------
__global__ void build_deg(const int* __restrict__ dst, int* __restrict__ deg, int E) {
  int e = blockIdx.x * 256 + threadIdx.x;
  if (e < E) atomicAdd(&deg[dst[e]], 1);
}

__global__ __launch_bounds__(256) void scan1(const int* __restrict__ deg,
                                             int* __restrict__ pref,
                                             int* __restrict__ bsum, int Nn) {
  __shared__ int wsum[4];
  int i = blockIdx.x * 256 + threadIdx.x;
  int lane = threadIdx.x & 63, w = threadIdx.x >> 6;
  int v = (i < Nn) ? deg[i] : 0;
  int s = v;
  for (int off = 1; off < 64; off <<= 1) {
    int t = __shfl_up(s, off, 64);
    if (lane >= off) s += t;
  }
  if (lane == 63) wsum[w] = s;
  __syncthreads();
  int add = 0;
  for (int k = 0; k < w; ++k) add += wsum[k];
  int incl = s + add;
  if (i < Nn) pref[i] = incl - v;
  if (threadIdx.x == 255) bsum[blockIdx.x] = incl;
}

__global__ __launch_bounds__(256) void scan2(int* __restrict__ bsum,
                                             int* __restrict__ row_ofs,
                                             int nb, int Nn) {
  __shared__ int wsum[4];
  int t = threadIdx.x;
  int lane = t & 63, w = t >> 6;
  int v = (t < nb) ? bsum[t] : 0;
  int s = v;
  for (int off = 1; off < 64; off <<= 1) {
    int u = __shfl_up(s, off, 64);
    if (lane >= off) s += u;
  }
  if (lane == 63) wsum[w] = s;
  __syncthreads();
  int add = 0;
  for (int k = 0; k < w; ++k) add += wsum[k];
  int incl = s + add;
  if (t < nb) bsum[t] = incl - v;
  if (t == 255) row_ofs[Nn] = incl;
}

__global__ __launch_bounds__(256) void scan3(const int* __restrict__ pref,
                                             const int* __restrict__ bsum,
                                             int* __restrict__ row_ofs,
                                             int* __restrict__ cursor, int Nn) {
  int i = blockIdx.x * 256 + threadIdx.x;
  if (i < Nn) {
    int r = pref[i] + bsum[blockIdx.x];
    row_ofs[i] = r;
    cursor[i] = r;
  }
}

__global__ void csr_fill(const int* __restrict__ src, const int* __restrict__ dst,
                         int* __restrict__ cursor, int* __restrict__ col, int E) {
  int e = blockIdx.x * 256 + threadIdx.x;
  if (e < E) {
    int p = atomicAdd(&cursor[dst[e]], 1);
    col[p] = src[e];
  }
}

// ------------- merged weight pack -------------
__global__ __launch_bounds__(256) void pack_all(
    const float* __restrict__ W1, const float* __restrict__ W2,
    const float* __restrict__ Wh1, u16* __restrict__ B1t,
    u16* __restrict__ B2t, u16* __restrict__ Bht) {
  int b = blockIdx.x;
  if (b < 1024) {
    int c = b >> 1;
    int k = (b & 1) * 256 + threadIdx.x;
    if (k < 384) {
      float v = (c < 256) ? W1[(size_t)k * 256 + c]
                          : W1[(size_t)(384 + k) * 256 + (c - 256)];
      B1t[(size_t)c * 384 + k] = f2bf(v);
    }
  } else if (b < 1536) {
    int c = b - 1024;
    int k = threadIdx.x;
    float v = (c < 256) ? W2[(size_t)k * 256 + c]
                        : W2[(size_t)(256 + k) * 256 + (c - 256)];
    B2t[(size_t)c * 256 + k] = f2bf(v);
  } else {
    int c = b - 1536;
    int k = threadIdx.x;
    Bht[(size_t)c * 256 + k] = f2bf(Wh1[(size_t)k * 128 + c]);
  }
}

// ------------- merged bias -------------
__global__ __launch_bounds__(384) void bias_all(
    const float* __restrict__ W1, const float* __restrict__ b1,
    const float* __restrict__ W2, const float* __restrict__ b2,
    const float* __restrict__ Wh1, const float* __restrict__ bh1,
    const float* __restrict__ q, float* __restrict__ cq1,
    float* __restrict__ cq2, float* __restrict__ cqh) {
  __shared__ float part[6];
  int b = blockIdx.x;
  const float* W; const float* bb; float* o; int ld, roff, c;
  if (b < 256)      { W = W1;  bb = b1;  o = cq1; ld = 256; roff = 768; c = b; }
  else if (b < 512) { W = W2;  bb = b2;  o = cq2; ld = 256; roff = 512; c = b - 256; }
  else              { W = Wh1; bb = bh1; o = cqh; ld = 128; roff = 256; c = b - 512; }
  int t = threadIdx.x;
  float p = q[t] * W[(size_t)(roff + t) * ld + c];
  for (int off = 32; off > 0; off >>= 1) p += __shfl_down(p, off, 64);
  if ((t & 63) == 0) part[t >> 6] = p;
  __syncthreads();
  if (t == 0) {
    float acc = bb[c];
    for (int w = 0; w < 6; ++w) acc += part[w];
    o[c] = acc;
  }
}

// ================= wide GEMM v14: back to r12 geometry (64 rows x 512 cols,
// A read ONCE, 72 KB LDS -> 2 blocks/CU) but with T3+T4 schedule:
// BK=32 double-buffer, stage(t+1) issued BEFORE compute(t), counted
// s_waitcnt vmcnt(N) + raw s_barrier so the A-prefetch loads stay in
// flight across the barrier (never drain vmcnt to 0 in the main loop).
#define W_NC 512
#define ES 520
#define V2_ASZ 2048               // 64 x 32 elems
#define V2_BSZ 16384              // 512 x 32 elems
#define V2_SMEM (2 * V2_ASZ + 2 * V2_BSZ)  // 36864 elems = 73728 B

// counted-wait barrier: stage glds must be done; `vm` younger loads
// (the A prefetch) may remain in flight.
#define V2_BARRIER(vm)                                                         \
  asm volatile("s_waitcnt vmcnt(" #vm ") lgkmcnt(0)\n\ts_barrier" ::: "memory");

#define V2_B_SETUP()                                                           \
  const u16* pbB[8];                                                           \
  _Pragma("unroll") for (int p = 0; p < 8; ++p) {                              \
    int L = p * 256 + tid;                                                     \
    int c = L >> 2, qs = L & 3;                                                \
    int g = qs ^ ((c >> 1) & 3);                                               \
    pbB[p] = Bt + (size_t)c * K + g * 8;                                       \
  }

#define V2_B_STAGE(DST)                                                        \
  _Pragma("unroll") for (int p = 0; p < 8; ++p) {                              \
    stage16(pbB[p], (DST) + (size_t)(p * 256 + wave * 64) * 8, lane);          \
    pbB[p] += 32;                                                              \
  }

#define V2_COMPUTE(LA, LB)                                                     \
  {                                                                            \
    short8 bfr[8];                                                             \
    _Pragma("unroll") for (int nt = 0; nt < 8; ++nt)                           \
      bfr[nt] =                                                                \
          *(const short8*)&(LB)[((wave * 128 + nt * 16 + m) * 4 + csel) * 8];  \
    _Pragma("unroll") for (int mt = 0; mt < 4; ++mt) {                         \
      short8 af = *(const short8*)&(LA)[((mt * 16 + m) * 4 + csel) * 8];       \
      _Pragma("unroll") for (int nt = 0; nt < 8; ++nt)                         \
        acc[mt][nt] = __builtin_amdgcn_mfma_f32_16x16x32_bf16(                 \
            af, bfr[nt], acc[mt][nt], 0, 0, 0);                                \
    }                                                                          \
  }

#define V2_EPILOGUE()                                                          \
  {                                                                            \
    u16* et = smem + 2 * V2_ASZ;                                               \
    _Pragma("unroll") for (int mt = 0; mt < 4; ++mt) {                         \
      __syncthreads();                                                         \
      _Pragma("unroll") for (int nt = 0; nt < 8; ++nt) {                       \
        int col = wave * 128 + nt * 16 + m;                                    \
        float bb = (col < bias_len) ? bias[col] : 0.0f;                        \
        _Pragma("unroll") for (int r = 0; r < 4; ++r) {                        \
          float v = acc[mt][nt][r] + bb;                                       \
          if (relu) v = fmaxf(v, 0.0f);                                        \
          et[(quad * 4 + r) * ES + col] = f2bf(v);                             \
        }                                                                      \
      }                                                                        \
      __syncthreads();                                                         \
      _Pragma("unroll") for (int p = 0; p < 4; ++p) {                          \
        int row_loc = p * 4 + wave;                                            \
        int grow = row0 + mt * 16 + row_loc;                                   \
        if (grow < M)                                                          \
          *(u16x8*)&C[(size_t)grow * W_NC + lane * 8] =                        \
              *(const u16x8*)&et[row_loc * ES + lane * 8];                     \
      }                                                                        \
    }                                                                          \
  }

// NOTE: NT must be even (K=384 -> 12, K=256 -> 8) so the last compute reads
// buffer 1 and the epilogue can safely reuse buffer 0's LDS.
__global__ __launch_bounds__(256, 2) void gemm512v2_f32a(
    const float* __restrict__ A, const u16* __restrict__ Bt,
    u16* __restrict__ C, const float* __restrict__ bias,
    int M, int K, int bias_len, int relu) {
  __shared__ __align__(16) u16 smem[V2_SMEM];
  u16* a0 = smem;
  u16* a1 = smem + V2_ASZ;
  u16* b0 = smem + 2 * V2_ASZ;
  u16* b1 = b0 + V2_BSZ;

  const int tid = threadIdx.x;
  const int lane = tid & 63;
  const int wave = tid >> 6;
  const int row0 = blockIdx.x * 64;
  const int m = lane & 15;
  const int quad = lane >> 4;
  const int csel = quad ^ ((m >> 1) & 3);

  const int rA = tid >> 2;
  const int qA = tid & 3;
  const int sA = rA * 4 + (qA ^ ((rA >> 1) & 3));
  int ga = row0 + rA; if (ga >= M) ga = M - 1;
  const float* pa = A + (size_t)ga * K + qA * 8;

  V2_B_SETUP()

  f32x4 acc[4][8] = {};

  // prologue: A(0) regs, stage tile 0, write A(0), prefetch A(1)
  f32x4 vlo = *(const f32x4*)pa, vhi = *(const f32x4*)(pa + 4);
  pa += 32;
  V2_B_STAGE(b0)
  {
    u16x8 h;
#pragma unroll
    for (int j = 0; j < 4; ++j) { h[j] = f2bf(vlo[j]); h[j + 4] = f2bf(vhi[j]); }
    *(u16x8*)&a0[sA * 8] = h;
  }
  {
    const float* pn = (32 < K) ? pa : A;
    vlo = *(const f32x4*)pn; vhi = *(const f32x4*)(pn + 4);
    pa += 32;
  }
  V2_BARRIER(2)

  const int NT = K >> 5;
  for (int t = 0; t < NT; ++t) {
    u16* la  = (t & 1) ? a1 : a0;
    u16* lb  = (t & 1) ? b1 : b0;
    u16* lan = (t & 1) ? a0 : a1;
    u16* lbn = (t & 1) ? b0 : b1;
    if (t + 1 < NT) {
      V2_B_STAGE(lbn)
      u16x8 h;
#pragma unroll
      for (int j = 0; j < 4; ++j) { h[j] = f2bf(vlo[j]); h[j + 4] = f2bf(vhi[j]); }
      *(u16x8*)&lan[sA * 8] = h;
      const float* pn = (t + 2 < NT) ? pa : A;
      vlo = *(const f32x4*)pn; vhi = *(const f32x4*)(pn + 4);
      pa += 32;
    }
    V2_COMPUTE(la, lb)
    V2_BARRIER(2)
  }

  V2_EPILOGUE()
}

__global__ __launch_bounds__(256, 2) void gemm512v2_bf16a(
    const u16* __restrict__ A, const u16* __restrict__ Bt,
    u16* __restrict__ C, const float* __restrict__ bias,
    int M, int K, int bias_len, int relu) {
  __shared__ __align__(16) u16 smem[V2_SMEM];
  u16* a0 = smem;
  u16* a1 = smem + V2_ASZ;
  u16* b0 = smem + 2 * V2_ASZ;
  u16* b1 = b0 + V2_BSZ;

  const int tid = threadIdx.x;
  const int lane = tid & 63;
  const int wave = tid >> 6;
  const int row0 = blockIdx.x * 64;
  const int m = lane & 15;
  const int quad = lane >> 4;
  const int csel = quad ^ ((m >> 1) & 3);

  const int rA = tid >> 2;
  const int qA = tid & 3;
  const int sA = rA * 4 + (qA ^ ((rA >> 1) & 3));
  int ga = row0 + rA; if (ga >= M) ga = M - 1;
  const u16* pa = A + (size_t)ga * K + qA * 8;

  V2_B_SETUP()

  f32x4 acc[4][8] = {};

  u16x8 va = *(const u16x8*)pa;
  pa += 32;
  V2_B_STAGE(b0)
  *(u16x8*)&a0[sA * 8] = va;
  {
    const u16* pn = (32 < K) ? pa : A;
    va = *(const u16x8*)pn;
    pa += 32;
  }
  V2_BARRIER(1)

  const int NT = K >> 5;
  for (int t = 0; t < NT; ++t) {
    u16* la  = (t & 1) ? a1 : a0;
    u16* lb  = (t & 1) ? b1 : b0;
    u16* lan = (t & 1) ? a0 : a1;
    u16* lbn = (t & 1) ? b0 : b1;
    if (t + 1 < NT) {
      V2_B_STAGE(lbn)
      *(u16x8*)&lan[sA * 8] = va;
      const u16* pn = (t + 2 < NT) ? pa : A;
      va = *(const u16x8*)pn;
      pa += 32;
    }
    V2_COMPUTE(la, lb)
    V2_BARRIER(1)
  }

  V2_EPILOGUE()
}

// ========== fused head (round-12 proven): out = relu(h2@Wh1h+cqh).Wh2+bh2 ====
#define BM 128
#define BK 32

__global__ __launch_bounds__(256) void gemm_head(
    const u16* __restrict__ A, const u16* __restrict__ Bt,
    const float* __restrict__ cqh, const float* __restrict__ Wh2,
    const float* __restrict__ bh2, float* __restrict__ out, int M, int K) {
  __shared__ __align__(16) u16 lds_a[BM * BK];
  __shared__ __align__(16) u16 lds_b[BM * BK];
  __shared__ float red[128][2];

  const int tid = threadIdx.x;
  const int lane = tid & 63;
  const int wave = tid >> 6;
  const int wm = wave & 1, wn = wave >> 1;
  const int row0 = blockIdx.x * BM;
  const int m = lane & 15;
  const int quad = lane >> 4;
  const int csel = quad ^ ((m >> 1) & 3);

  const int r0 = tid >> 2, r1 = 64 + r0;
  const int cs = tid & 3;
  const int s0 = r0 * 4 + (cs ^ ((r0 >> 1) & 3));
  const int s1 = r1 * 4 + (cs ^ ((r1 >> 1) & 3));
  const int cb0 = cs ^ ((r0 >> 1) & 3);
  const int cb1 = cs ^ ((r1 >> 1) & 3);
  int ga0 = row0 + r0; if (ga0 >= M) ga0 = M - 1;
  int ga1 = row0 + r1; if (ga1 >= M) ga1 = M - 1;
  const u16* pa0 = A + (size_t)ga0 * K + cs * 8;
  const u16* pa1 = A + (size_t)ga1 * K + cs * 8;
  const u16* pb0 = Bt + (size_t)r0 * K + cb0 * 8;
  const u16* pb1 = Bt + (size_t)r1 * K + cb1 * 8;
  u16* lb0 = lds_b + (size_t)(wave * 64) * 8;
  u16* lb1 = lds_b + (size_t)(256 + wave * 64) * 8;

  f32x4 acc[4][4] = {};

  u16x8 va0 = *(const u16x8*)pa0; pa0 += BK;
  u16x8 va1 = *(const u16x8*)pa1; pa1 += BK;

  for (int k0 = 0; k0 < K; k0 += BK) {
    __syncthreads();
    stage16(pb0, lb0, lane); pb0 += BK;
    stage16(pb1, lb1, lane); pb1 += BK;
    *(u16x8*)&lds_a[s0 * 8] = va0;
    *(u16x8*)&lds_a[s1 * 8] = va1;
    const u16* n0 = (k0 + BK < K) ? pa0 : A;
    const u16* n1 = (k0 + BK < K) ? pa1 : A;
    u16x8 w0 = *(const u16x8*)n0;
    u16x8 w1 = *(const u16x8*)n1;
    pa0 += BK; pa1 += BK;
    __syncthreads();

    short8 af[4], bfv[4];
#pragma unroll
    for (int mt = 0; mt < 4; ++mt)
      af[mt] = *(const short8*)&lds_a[((wm * 64 + mt * 16 + m) * 4 + csel) * 8];
#pragma unroll
    for (int nt = 0; nt < 4; ++nt)
      bfv[nt] = *(const short8*)&lds_b[((wn * 64 + nt * 16 + m) * 4 + csel) * 8];
#pragma unroll
    for (int mt = 0; mt < 4; ++mt)
#pragma unroll
      for (int nt = 0; nt < 4; ++nt)
        acc[mt][nt] = __builtin_amdgcn_mfma_f32_16x16x32_bf16(
            af[mt], bfv[nt], acc[mt][nt], 0, 0, 0);
    va0 = w0; va1 = w1;
  }

  float part[4][4];
#pragma unroll
  for (int mt = 0; mt < 4; ++mt)
#pragma unroll
    for (int r = 0; r < 4; ++r) part[mt][r] = 0.0f;
#pragma unroll
  for (int nt = 0; nt < 4; ++nt) {
    int col = wn * 64 + nt * 16 + m;
    float bb = cqh[col];
    float w2 = Wh2[col];
#pragma unroll
    for (int mt = 0; mt < 4; ++mt)
#pragma unroll
      for (int r = 0; r < 4; ++r)
        part[mt][r] += fmaxf(acc[mt][nt][r] + bb, 0.0f) * w2;
  }
#pragma unroll
  for (int off = 8; off > 0; off >>= 1)
#pragma unroll
    for (int mt = 0; mt < 4; ++mt)
#pragma unroll
      for (int r = 0; r < 4; ++r)
        part[mt][r] += __shfl_xor(part[mt][r], off, 64);
  if (m == 0) {
#pragma unroll
    for (int mt = 0; mt < 4; ++mt)
#pragma unroll
      for (int r = 0; r < 4; ++r)
        red[wm * 64 + mt * 16 + quad * 4 + r][wn] = part[mt][r];
  }
  __syncthreads();
  if (tid < 128) {
    int grow = row0 + tid;
    if (grow < M) out[grow] = red[tid][0] + red[tid][1] + bh2[0];
  }
}

// ---------------- aggregation: H[i] = relu(u_i + (y_i + sum_j y_j)/(deg+1))
__global__ __launch_bounds__(256) void aggregate(
    const u16* __restrict__ C, const int* __restrict__ row_ofs,
    const int* __restrict__ col_idx, u16* __restrict__ H, int Nn) {
  int node = blockIdx.x * 8 + (threadIdx.x >> 5);
  if (node >= Nn) return;
  int l = threadIdx.x & 31;
  int s = row_ofs[node], e = row_ofs[node + 1];
  float inv = 1.0f / (float)(e - s + 1);
  const u16* crow = C + (size_t)node * 512;
  u16x8 y0 = *(const u16x8*)(crow + 256 + l * 8);
  float a[8];
#pragma unroll
  for (int j = 0; j < 8; ++j) a[j] = bf2f(y0[j]);
  int t = s;
  for (; t + 4 <= e; t += 4) {
    int j0 = col_idx[t], j1 = col_idx[t + 1], j2 = col_idx[t + 2], j3 = col_idx[t + 3];
    u16x8 v0 = *(const u16x8*)(C + (size_t)j0 * 512 + 256 + l * 8);
    u16x8 v1 = *(const u16x8*)(C + (size_t)j1 * 512 + 256 + l * 8);
    u16x8 v2 = *(const u16x8*)(C + (size_t)j2 * 512 + 256 + l * 8);
    u16x8 v3 = *(const u16x8*)(C + (size_t)j3 * 512 + 256 + l * 8);
#pragma unroll
    for (int j = 0; j < 8; ++j)
      a[j] += (bf2f(v0[j]) + bf2f(v1[j])) + (bf2f(v2[j]) + bf2f(v3[j]));
  }
  for (; t < e; ++t) {
    int jj = col_idx[t];
    u16x8 vj = *(const u16x8*)(C + (size_t)jj * 512 + 256 + l * 8);
#pragma unroll
    for (int j = 0; j < 8; ++j) a[j] += bf2f(vj[j]);
  }
  u16x8 u = *(const u16x8*)(crow + l * 8);
  u16x8 o;
#pragma unroll
  for (int j = 0; j < 8; ++j)
    o[j] = f2bf(fmaxf(bf2f(u[j]) + a[j] * inv, 0.0f));
  *(u16x8*)(H + (size_t)node * 256 + l * 8) = o;
}

extern "C" void kernel_launch(void* const* d_in, const int* in_sizes, int n_in,
                              void* d_out, int out_size, void* d_ws, size_t ws_size,
                              hipStream_t stream) {
  const float* x   = (const float*)d_in[0];
  const int*   ei  = (const int*)d_in[1];
  const float* q   = (const float*)d_in[2];
  const float* W1  = (const float*)d_in[3];
  const float* b1  = (const float*)d_in[4];
  const float* W2  = (const float*)d_in[5];
  const float* b2  = (const float*)d_in[6];
  const float* Wh1 = (const float*)d_in[7];
  const float* bh1 = (const float*)d_in[8];
  const float* Wh2 = (const float*)d_in[9];
  const float* bh2 = (const float*)d_in[10];

  const int N = in_sizes[0] / 384;
  const int E = in_sizes[1] / 2;
  const int Npad = ((N + 127) / 128) * 128;
  const int* esrc = ei;
  const int* edst = ei + E;

  size_t off = 0;
  auto alloc = [&](size_t bytes) -> void* {
    void* p = (char*)d_ws + off;
    off += (bytes + 255) & ~(size_t)255;
    return p;
  };
  int* deg     = (int*)alloc((size_t)N * 4);
  int* row_ofs = (int*)alloc((size_t)(N + 1) * 4);
  int* cursor  = (int*)alloc((size_t)N * 4);
  int* colidx  = (int*)alloc((size_t)E * 4);
  int* pref    = (int*)alloc((size_t)N * 4);
  int* bsum    = (int*)alloc(256 * 4);
  u16* B1t = (u16*)alloc((size_t)512 * 384 * 2);
  u16* B2t = (u16*)alloc((size_t)512 * 256 * 2);
  u16* Bht = (u16*)alloc((size_t)128 * 256 * 2);
  float* cq1 = (float*)alloc(256 * 4);
  float* cq2 = (float*)alloc(256 * 4);
  float* cqh = (float*)alloc(128 * 4);
  u16* Cbuf = (u16*)alloc((size_t)Npad * 512 * 2);
  u16* Hbuf = (u16*)alloc((size_t)Npad * 256 * 2);

  (void)hipMemsetAsync(deg, 0, (size_t)N * 4, stream);
  int eb = (E + 255) / 256;
  int nb = (N + 255) / 256;
  build_deg<<<eb, 256, 0, stream>>>(edst, deg, E);
  scan1<<<nb, 256, 0, stream>>>(deg, pref, bsum, N);
  scan2<<<1, 256, 0, stream>>>(bsum, row_ofs, nb, N);
  scan3<<<nb, 256, 0, stream>>>(pref, bsum, row_ofs, cursor, N);
  csr_fill<<<eb, 256, 0, stream>>>(esrc, edst, cursor, colidx, E);

  pack_all<<<1664, 256, 0, stream>>>(W1, W2, Wh1, B1t, B2t, Bht);
  bias_all<<<640, 384, 0, stream>>>(W1, b1, W2, b2, Wh1, bh1, q, cq1, cq2, cqh);

  int gb64 = (N + 63) / 64;
  int mb = Npad / 128;
  int nb8 = (N + 7) / 8;
  // layer 1
  gemm512v2_f32a<<<gb64, 256, 0, stream>>>(x, B1t, Cbuf, cq1, N, 384, 256, 0);
  aggregate<<<nb8, 256, 0, stream>>>(Cbuf, row_ofs, colidx, Hbuf, N);
  // layer 2
  gemm512v2_bf16a<<<gb64, 256, 0, stream>>>(Hbuf, B2t, Cbuf, cq2, N, 256, 256, 0);
  aggregate<<<nb8, 256, 0, stream>>>(Cbuf, row_ofs, colidx, Hbuf, N);
  // fused head
  gemm_head<<<mb, 256, 0, stream>>>(Hbuf, Bht, cqh, Wh2, bh2, (float*)d_out, N, 256);
}

// Round 3
// 343.714 us; speedup vs baseline: 1.0181x; 1.0131x over previous
//
#include <hip/hip_runtime.h>
#include <cstdint>
#include <cstddef>

typedef unsigned short u16;
typedef short short8 __attribute__((ext_vector_type(8)));
typedef unsigned short u16x8 __attribute__((ext_vector_type(8)));
typedef unsigned short u16x4 __attribute__((ext_vector_type(4)));
typedef float f32x4 __attribute__((ext_vector_type(4)));

#define DEVI __device__ __forceinline__

#if defined(__has_builtin)
#if __has_builtin(__builtin_amdgcn_global_load_lds)
#define USE_GLD 1
#endif
#endif

DEVI float bf2f(u16 u) { return __uint_as_float(((unsigned)u) << 16); }
DEVI u16 f2bf(float f) {
  unsigned u = __float_as_uint(f);
  u += 0x7FFFu + ((u >> 16) & 1u);  // RNE
  return (u16)(u >> 16);
}

DEVI void stage16(const u16* __restrict__ g, u16* lds_base, int lane) {
#ifdef USE_GLD
  __builtin_amdgcn_global_load_lds(
      (const __attribute__((address_space(1))) unsigned int*)g,
      (__attribute__((address_space(3))) unsigned int*)lds_base, 16, 0, 0);
#else
  *(u16x8*)(lds_base + lane * 8) = *(const u16x8*)g;
#endif
}

// ---------------- CSR build ----------------
__global__ void build_deg(const int* __restrict__ dst, int* __restrict__ deg, int E) {
  int e = blockIdx.x * 256 + threadIdx.x;
  if (e < E) atomicAdd(&deg[dst[e]], 1);
}

__global__ __launch_bounds__(256) void scan1(const int* __restrict__ deg,
                                             int* __restrict__ pref,
                                             int* __restrict__ bsum, int Nn) {
  __shared__ int wsum[4];
  int i = blockIdx.x * 256 + threadIdx.x;
  int lane = threadIdx.x & 63, w = threadIdx.x >> 6;
  int v = (i < Nn) ? deg[i] : 0;
  int s = v;
  for (int off = 1; off < 64; off <<= 1) {
    int t = __shfl_up(s, off, 64);
    if (lane >= off) s += t;
  }
  if (lane == 63) wsum[w] = s;
  __syncthreads();
  int add = 0;
  for (int k = 0; k < w; ++k) add += wsum[k];
  int incl = s + add;
  if (i < Nn) pref[i] = incl - v;
  if (threadIdx.x == 255) bsum[blockIdx.x] = incl;
}

__global__ __launch_bounds__(256) void scan2(int* __restrict__ bsum,
                                             int* __restrict__ row_ofs,
                                             int nb, int Nn) {
  __shared__ int wsum[4];
  int t = threadIdx.x;
  int lane = t & 63, w = t >> 6;
  int v = (t < nb) ? bsum[t] : 0;
  int s = v;
  for (int off = 1; off < 64; off <<= 1) {
    int u = __shfl_up(s, off, 64);
    if (lane >= off) s += u;
  }
  if (lane == 63) wsum[w] = s;
  __syncthreads();
  int add = 0;
  for (int k = 0; k < w; ++k) add += wsum[k];
  int incl = s + add;
  if (t < nb) bsum[t] = incl - v;
  if (t == 255) row_ofs[Nn] = incl;
}

__global__ __launch_bounds__(256) void scan3(const int* __restrict__ pref,
                                             const int* __restrict__ bsum,
                                             int* __restrict__ row_ofs,
                                             int* __restrict__ cursor, int Nn) {
  int i = blockIdx.x * 256 + threadIdx.x;
  if (i < Nn) {
    int r = pref[i] + bsum[blockIdx.x];
    row_ofs[i] = r;
    cursor[i] = r;
  }
}

__global__ void csr_fill(const int* __restrict__ src, const int* __restrict__ dst,
                         int* __restrict__ cursor, int* __restrict__ col, int E) {
  int e = blockIdx.x * 256 + threadIdx.x;
  if (e < E) {
    int p = atomicAdd(&cursor[dst[e]], 1);
    col[p] = src[e];
  }
}

// ------------- merged weight pack -------------
__global__ __launch_bounds__(256) void pack_all(
    const float* __restrict__ W1, const float* __restrict__ W2,
    const float* __restrict__ Wh1, u16* __restrict__ B1t,
    u16* __restrict__ B2t, u16* __restrict__ Bht) {
  int b = blockIdx.x;
  if (b < 1024) {
    int c = b >> 1;
    int k = (b & 1) * 256 + threadIdx.x;
    if (k < 384) {
      float v = (c < 256) ? W1[(size_t)k * 256 + c]
                          : W1[(size_t)(384 + k) * 256 + (c - 256)];
      B1t[(size_t)c * 384 + k] = f2bf(v);
    }
  } else if (b < 1536) {
    int c = b - 1024;
    int k = threadIdx.x;
    float v = (c < 256) ? W2[(size_t)k * 256 + c]
                        : W2[(size_t)(256 + k) * 256 + (c - 256)];
    B2t[(size_t)c * 256 + k] = f2bf(v);
  } else {
    int c = b - 1536;
    int k = threadIdx.x;
    Bht[(size_t)c * 256 + k] = f2bf(Wh1[(size_t)k * 128 + c]);
  }
}

// ------------- merged bias -------------
__global__ __launch_bounds__(384) void bias_all(
    const float* __restrict__ W1, const float* __restrict__ b1,
    const float* __restrict__ W2, const float* __restrict__ b2,
    const float* __restrict__ Wh1, const float* __restrict__ bh1,
    const float* __restrict__ q, float* __restrict__ cq1,
    float* __restrict__ cq2, float* __restrict__ cqh) {
  __shared__ float part[6];
  int b = blockIdx.x;
  const float* W; const float* bb; float* o; int ld, roff, c;
  if (b < 256)      { W = W1;  bb = b1;  o = cq1; ld = 256; roff = 768; c = b; }
  else if (b < 512) { W = W2;  bb = b2;  o = cq2; ld = 256; roff = 512; c = b - 256; }
  else              { W = Wh1; bb = bh1; o = cqh; ld = 128; roff = 256; c = b - 512; }
  int t = threadIdx.x;
  float p = q[t] * W[(size_t)(roff + t) * ld + c];
  for (int off = 32; off > 0; off >>= 1) p += __shfl_down(p, off, 64);
  if ((t & 63) == 0) part[t >> 6] = p;
  __syncthreads();
  if (t == 0) {
    float acc = bb[c];
    for (int w = 0; w < 6; ++w) acc += part[w];
    o[c] = acc;
  }
}

// ================= wide GEMM v15: r12's proven schedule, geometry scaled to
// 128 rows x 512 cols in ONE block (A read once, B-restage traffic HALVED:
// 391 blocks x 384 KB instead of 782 x 384 KB). 512 threads = 8 waves in a
// 2x4 grid of 64x128 wave-tiles. LDS 80 KB (A 2x8KB chunk-pair + B 2x32KB).
#define W_NC 512
#define ES 520
#define V3_ACH 4096                  // 128 x 32 elems (one 32-K chunk of A)
#define V3_BCH 16384                 // 512 x 32 elems (one 32-K chunk of B)
#define V3_SMEM (2 * V3_ACH + 2 * V3_BCH)  // 40960 elems = 81920 B

#define V3_B_SETUP()                                                           \
  const u16* pbB[4];                                                           \
  _Pragma("unroll") for (int p = 0; p < 4; ++p) {                              \
    int L = p * 512 + tid;                                                     \
    int c = L >> 2, qs = L & 3;                                                \
    int g = qs ^ ((c >> 1) & 3);                                               \
    pbB[p] = Bt + (size_t)c * K + g * 8;                                       \
  }

// stage both 32-K chunks of the current 64-K tile (b0 and b1 regions)
#define V3_B_STAGE2()                                                          \
  _Pragma("unroll") for (int p = 0; p < 4; ++p) {                              \
    u16* d = lds_b0 + (size_t)(p * 512 + wave * 64) * 8;                       \
    stage16(pbB[p], d, lane);                                                  \
    stage16(pbB[p] + 32, d + V3_BCH, lane);                                    \
    pbB[p] += 64;                                                              \
  }

#define V3_COMPUTE(LA, LB)                                                     \
  {                                                                            \
    short8 bfr[8];                                                             \
    _Pragma("unroll") for (int nt = 0; nt < 8; ++nt)                           \
      bfr[nt] =                                                                \
          *(const short8*)&(LB)[((wc * 128 + nt * 16 + m) * 4 + csel) * 8];    \
    _Pragma("unroll") for (int mt = 0; mt < 4; ++mt) {                         \
      short8 af =                                                              \
          *(const short8*)&(LA)[((wr * 64 + mt * 16 + m) * 4 + csel) * 8];     \
      _Pragma("unroll") for (int nt = 0; nt < 8; ++nt)                         \
        acc[mt][nt] = __builtin_amdgcn_mfma_f32_16x16x32_bf16(                 \
            af, bfr[nt], acc[mt][nt], 0, 0, 0);                                \
    }                                                                          \
  }

// epilogue: per mt, 32 rows (wr=0: mt*16.., wr=1: 64+mt*16..) through LDS
#define V3_EPILOGUE()                                                          \
  {                                                                            \
    u16* et = smem;                                                            \
    _Pragma("unroll") for (int mt = 0; mt < 4; ++mt) {                         \
      __syncthreads();                                                         \
      _Pragma("unroll") for (int nt = 0; nt < 8; ++nt) {                       \
        int col = wc * 128 + nt * 16 + m;                                      \
        float bb = (col < bias_len) ? bias[col] : 0.0f;                        \
        _Pragma("unroll") for (int r = 0; r < 4; ++r) {                        \
          float v = acc[mt][nt][r] + bb;                                       \
          if (relu) v = fmaxf(v, 0.0f);                                        \
          et[(wr * 16 + quad * 4 + r) * ES + col] = f2bf(v);                   \
        }                                                                      \
      }                                                                        \
      __syncthreads();                                                         \
      _Pragma("unroll") for (int rep = 0; rep < 4; ++rep) {                    \
        int idx = rep * 512 + tid;                                             \
        int row = idx >> 6, ch = idx & 63;                                     \
        int grow = row0 + (row >> 4) * 64 + mt * 16 + (row & 15);              \
        if (grow < M)                                                          \
          *(u16x8*)&C[(size_t)grow * W_NC + ch * 8] =                          \
              *(const u16x8*)&et[row * ES + ch * 8];                           \
      }                                                                        \
    }                                                                          \
  }

__global__ __launch_bounds__(512, 2) void gemm512w_f32a(
    const float* __restrict__ A, const u16* __restrict__ Bt,
    u16* __restrict__ C, const float* __restrict__ bias,
    int M, int K, int bias_len, int relu) {
  __shared__ __align__(16) u16 smem[V3_SMEM];
  u16* lds_a0 = smem;
  u16* lds_a1 = smem + V3_ACH;
  u16* lds_b0 = smem + 2 * V3_ACH;
  u16* lds_b1 = lds_b0 + V3_BCH;

  const int tid = threadIdx.x;
  const int lane = tid & 63;
  const int wave = tid >> 6;     // 0..7
  const int wr = wave >> 2;      // 0..1 row half
  const int wc = wave & 3;       // 0..3 col quarter
  const int row0 = blockIdx.x * 128;
  const int m = lane & 15;
  const int quad = lane >> 4;
  const int csel = quad ^ ((m >> 1) & 3);

  const int rA = tid >> 2;       // 0..127
  const int qA = tid & 3;
  const int sA = rA * 4 + (qA ^ ((rA >> 1) & 3));
  int ga = row0 + rA; if (ga >= M) ga = M - 1;
  const float* pa = A + (size_t)ga * K + qA * 8;

  V3_B_SETUP()

  f32x4 acc[4][8] = {};

  f32x4 v0a = *(const f32x4*)pa, v0b = *(const f32x4*)(pa + 4);
  f32x4 v1a = *(const f32x4*)(pa + 32), v1b = *(const f32x4*)(pa + 36);
  pa += 64;

  for (int k0 = 0; k0 < K; k0 += 64) {
    __syncthreads();
    V3_B_STAGE2()
    u16x8 h0, h1;
#pragma unroll
    for (int j = 0; j < 4; ++j) {
      h0[j] = f2bf(v0a[j]); h0[j + 4] = f2bf(v0b[j]);
      h1[j] = f2bf(v1a[j]); h1[j + 4] = f2bf(v1b[j]);
    }
    *(u16x8*)&lds_a0[sA * 8] = h0;
    *(u16x8*)&lds_a1[sA * 8] = h1;
    const float* pn = (k0 + 64 < K) ? pa : A;
    f32x4 n0a = *(const f32x4*)pn, n0b = *(const f32x4*)(pn + 4);
    f32x4 n1a = *(const f32x4*)(pn + 32), n1b = *(const f32x4*)(pn + 36);
    pa += 64;
    __syncthreads();
    V3_COMPUTE(lds_a0, lds_b0)
    V3_COMPUTE(lds_a1, lds_b1)
    v0a = n0a; v0b = n0b; v1a = n1a; v1b = n1b;
  }

  V3_EPILOGUE()
}

__global__ __launch_bounds__(512, 2) void gemm512w_bf16a(
    const u16* __restrict__ A, const u16* __restrict__ Bt,
    u16* __restrict__ C, const float* __restrict__ bias,
    int M, int K, int bias_len, int relu) {
  __shared__ __align__(16) u16 smem[V3_SMEM];
  u16* lds_a0 = smem;
  u16* lds_a1 = smem + V3_ACH;
  u16* lds_b0 = smem + 2 * V3_ACH;
  u16* lds_b1 = lds_b0 + V3_BCH;

  const int tid = threadIdx.x;
  const int lane = tid & 63;
  const int wave = tid >> 6;
  const int wr = wave >> 2;
  const int wc = wave & 3;
  const int row0 = blockIdx.x * 128;
  const int m = lane & 15;
  const int quad = lane >> 4;
  const int csel = quad ^ ((m >> 1) & 3);

  const int rA = tid >> 2;
  const int qA = tid & 3;
  const int sA = rA * 4 + (qA ^ ((rA >> 1) & 3));
  int ga = row0 + rA; if (ga >= M) ga = M - 1;
  const u16* pa = A + (size_t)ga * K + qA * 8;

  V3_B_SETUP()

  f32x4 acc[4][8] = {};

  u16x8 va0 = *(const u16x8*)pa;
  u16x8 va1 = *(const u16x8*)(pa + 32);
  pa += 64;

  for (int k0 = 0; k0 < K; k0 += 64) {
    __syncthreads();
    V3_B_STAGE2()
    *(u16x8*)&lds_a0[sA * 8] = va0;
    *(u16x8*)&lds_a1[sA * 8] = va1;
    const u16* pn = (k0 + 64 < K) ? pa : A;
    u16x8 na0 = *(const u16x8*)pn;
    u16x8 na1 = *(const u16x8*)(pn + 32);
    pa += 64;
    __syncthreads();
    V3_COMPUTE(lds_a0, lds_b0)
    V3_COMPUTE(lds_a1, lds_b1)
    va0 = na0; va1 = na1;
  }

  V3_EPILOGUE()
}

// ========== fused head (round-12 proven): out = relu(h2@Wh1h+cqh).Wh2+bh2 ====
#define BM 128
#define BK 32

__global__ __launch_bounds__(256) void gemm_head(
    const u16* __restrict__ A, const u16* __restrict__ Bt,
    const float* __restrict__ cqh, const float* __restrict__ Wh2,
    const float* __restrict__ bh2, float* __restrict__ out, int M, int K) {
  __shared__ __align__(16) u16 lds_a[BM * BK];
  __shared__ __align__(16) u16 lds_b[BM * BK];
  __shared__ float red[128][2];

  const int tid = threadIdx.x;
  const int lane = tid & 63;
  const int wave = tid >> 6;
  const int wm = wave & 1, wn = wave >> 1;
  const int row0 = blockIdx.x * BM;
  const int m = lane & 15;
  const int quad = lane >> 4;
  const int csel = quad ^ ((m >> 1) & 3);

  const int r0 = tid >> 2, r1 = 64 + r0;
  const int cs = tid & 3;
  const int s0 = r0 * 4 + (cs ^ ((r0 >> 1) & 3));
  const int s1 = r1 * 4 + (cs ^ ((r1 >> 1) & 3));
  const int cb0 = cs ^ ((r0 >> 1) & 3);
  const int cb1 = cs ^ ((r1 >> 1) & 3);
  int ga0 = row0 + r0; if (ga0 >= M) ga0 = M - 1;
  int ga1 = row0 + r1; if (ga1 >= M) ga1 = M - 1;
  const u16* pa0 = A + (size_t)ga0 * K + cs * 8;
  const u16* pa1 = A + (size_t)ga1 * K + cs * 8;
  const u16* pb0 = Bt + (size_t)r0 * K + cb0 * 8;
  const u16* pb1 = Bt + (size_t)r1 * K + cb1 * 8;
  u16* lb0 = lds_b + (size_t)(wave * 64) * 8;
  u16* lb1 = lds_b + (size_t)(256 + wave * 64) * 8;

  f32x4 acc[4][4] = {};

  u16x8 va0 = *(const u16x8*)pa0; pa0 += BK;
  u16x8 va1 = *(const u16x8*)pa1; pa1 += BK;

  for (int k0 = 0; k0 < K; k0 += BK) {
    __syncthreads();
    stage16(pb0, lb0, lane); pb0 += BK;
    stage16(pb1, lb1, lane); pb1 += BK;
    *(u16x8*)&lds_a[s0 * 8] = va0;
    *(u16x8*)&lds_a[s1 * 8] = va1;
    const u16* n0 = (k0 + BK < K) ? pa0 : A;
    const u16* n1 = (k0 + BK < K) ? pa1 : A;
    u16x8 w0 = *(const u16x8*)n0;
    u16x8 w1 = *(const u16x8*)n1;
    pa0 += BK; pa1 += BK;
    __syncthreads();

    short8 af[4], bfv[4];
#pragma unroll
    for (int mt = 0; mt < 4; ++mt)
      af[mt] = *(const short8*)&lds_a[((wm * 64 + mt * 16 + m) * 4 + csel) * 8];
#pragma unroll
    for (int nt = 0; nt < 4; ++nt)
      bfv[nt] = *(const short8*)&lds_b[((wn * 64 + nt * 16 + m) * 4 + csel) * 8];
#pragma unroll
    for (int mt = 0; mt < 4; ++mt)
#pragma unroll
      for (int nt = 0; nt < 4; ++nt)
        acc[mt][nt] = __builtin_amdgcn_mfma_f32_16x16x32_bf16(
            af[mt], bfv[nt], acc[mt][nt], 0, 0, 0);
    va0 = w0; va1 = w1;
  }

  float part[4][4];
#pragma unroll
  for (int mt = 0; mt < 4; ++mt)
#pragma unroll
    for (int r = 0; r < 4; ++r) part[mt][r] = 0.0f;
#pragma unroll
  for (int nt = 0; nt < 4; ++nt) {
    int col = wn * 64 + nt * 16 + m;
    float bb = cqh[col];
    float w2 = Wh2[col];
#pragma unroll
    for (int mt = 0; mt < 4; ++mt)
#pragma unroll
      for (int r = 0; r < 4; ++r)
        part[mt][r] += fmaxf(acc[mt][nt][r] + bb, 0.0f) * w2;
  }
#pragma unroll
  for (int off = 8; off > 0; off >>= 1)
#pragma unroll
    for (int mt = 0; mt < 4; ++mt)
#pragma unroll
      for (int r = 0; r < 4; ++r)
        part[mt][r] += __shfl_xor(part[mt][r], off, 64);
  if (m == 0) {
#pragma unroll
    for (int mt = 0; mt < 4; ++mt)
#pragma unroll
      for (int r = 0; r < 4; ++r)
        red[wm * 64 + mt * 16 + quad * 4 + r][wn] = part[mt][r];
  }
  __syncthreads();
  if (tid < 128) {
    int grow = row0 + tid;
    if (grow < M) out[grow] = red[tid][0] + red[tid][1] + bh2[0];
  }
}

// ---------------- aggregation: H[i] = relu(u_i + (y_i + sum_j y_j)/(deg+1))
__global__ __launch_bounds__(256) void aggregate(
    const u16* __restrict__ C, const int* __restrict__ row_ofs,
    const int* __restrict__ col_idx, u16* __restrict__ H, int Nn) {
  int node = blockIdx.x * 8 + (threadIdx.x >> 5);
  if (node >= Nn) return;
  int l = threadIdx.x & 31;
  int s = row_ofs[node], e = row_ofs[node + 1];
  float inv = 1.0f / (float)(e - s + 1);
  const u16* crow = C + (size_t)node * 512;
  u16x8 y0 = *(const u16x8*)(crow + 256 + l * 8);
  float a[8];
#pragma unroll
  for (int j = 0; j < 8; ++j) a[j] = bf2f(y0[j]);
  int t = s;
  for (; t + 4 <= e; t += 4) {
    int j0 = col_idx[t], j1 = col_idx[t + 1], j2 = col_idx[t + 2], j3 = col_idx[t + 3];
    u16x8 v0 = *(const u16x8*)(C + (size_t)j0 * 512 + 256 + l * 8);
    u16x8 v1 = *(const u16x8*)(C + (size_t)j1 * 512 + 256 + l * 8);
    u16x8 v2 = *(const u16x8*)(C + (size_t)j2 * 512 + 256 + l * 8);
    u16x8 v3 = *(const u16x8*)(C + (size_t)j3 * 512 + 256 + l * 8);
#pragma unroll
    for (int j = 0; j < 8; ++j)
      a[j] += (bf2f(v0[j]) + bf2f(v1[j])) + (bf2f(v2[j]) + bf2f(v3[j]));
  }
  for (; t < e; ++t) {
    int jj = col_idx[t];
    u16x8 vj = *(const u16x8*)(C + (size_t)jj * 512 + 256 + l * 8);
#pragma unroll
    for (int j = 0; j < 8; ++j) a[j] += bf2f(vj[j]);
  }
  u16x8 u = *(const u16x8*)(crow + l * 8);
  u16x8 o;
#pragma unroll
  for (int j = 0; j < 8; ++j)
    o[j] = f2bf(fmaxf(bf2f(u[j]) + a[j] * inv, 0.0f));
  *(u16x8*)(H + (size_t)node * 256 + l * 8) = o;
}

extern "C" void kernel_launch(void* const* d_in, const int* in_sizes, int n_in,
                              void* d_out, int out_size, void* d_ws, size_t ws_size,
                              hipStream_t stream) {
  const float* x   = (const float*)d_in[0];
  const int*   ei  = (const int*)d_in[1];
  const float* q   = (const float*)d_in[2];
  const float* W1  = (const float*)d_in[3];
  const float* b1  = (const float*)d_in[4];
  const float* W2  = (const float*)d_in[5];
  const float* b2  = (const float*)d_in[6];
  const float* Wh1 = (const float*)d_in[7];
  const float* bh1 = (const float*)d_in[8];
  const float* Wh2 = (const float*)d_in[9];
  const float* bh2 = (const float*)d_in[10];

  const int N = in_sizes[0] / 384;
  const int E = in_sizes[1] / 2;
  const int Npad = ((N + 127) / 128) * 128;
  const int* esrc = ei;
  const int* edst = ei + E;

  size_t off = 0;
  auto alloc = [&](size_t bytes) -> void* {
    void* p = (char*)d_ws + off;
    off += (bytes + 255) & ~(size_t)255;
    return p;
  };
  int* deg     = (int*)alloc((size_t)N * 4);
  int* row_ofs = (int*)alloc((size_t)(N + 1) * 4);
  int* cursor  = (int*)alloc((size_t)N * 4);
  int* colidx  = (int*)alloc((size_t)E * 4);
  int* pref    = (int*)alloc((size_t)N * 4);
  int* bsum    = (int*)alloc(256 * 4);
  u16* B1t = (u16*)alloc((size_t)512 * 384 * 2);
  u16* B2t = (u16*)alloc((size_t)512 * 256 * 2);
  u16* Bht = (u16*)alloc((size_t)128 * 256 * 2);
  float* cq1 = (float*)alloc(256 * 4);
  float* cq2 = (float*)alloc(256 * 4);
  float* cqh = (float*)alloc(128 * 4);
  u16* Cbuf = (u16*)alloc((size_t)Npad * 512 * 2);
  u16* Hbuf = (u16*)alloc((size_t)Npad * 256 * 2);

  (void)hipMemsetAsync(deg, 0, (size_t)N * 4, stream);
  int eb = (E + 255) / 256;
  int nb = (N + 255) / 256;
  build_deg<<<eb, 256, 0, stream>>>(edst, deg, E);
  scan1<<<nb, 256, 0, stream>>>(deg, pref, bsum, N);
  scan2<<<1, 256, 0, stream>>>(bsum, row_ofs, nb, N);
  scan3<<<nb, 256, 0, stream>>>(pref, bsum, row_ofs, cursor, N);
  csr_fill<<<eb, 256, 0, stream>>>(esrc, edst, cursor, colidx, E);

  pack_all<<<1664, 256, 0, stream>>>(W1, W2, Wh1, B1t, B2t, Bht);
  bias_all<<<640, 384, 0, stream>>>(W1, b1, W2, b2, Wh1, bh1, q, cq1, cq2, cqh);

  int gb128 = (N + 127) / 128;
  int mb = Npad / 128;
  int nb8 = (N + 7) / 8;
  // layer 1
  gemm512w_f32a<<<gb128, 512, 0, stream>>>(x, B1t, Cbuf, cq1, N, 384, 256, 0);
  aggregate<<<nb8, 256, 0, stream>>>(Cbuf, row_ofs, colidx, Hbuf, N);
  // layer 2
  gemm512w_bf16a<<<gb128, 512, 0, stream>>>(Hbuf, B2t, Cbuf, cq2, N, 256, 256, 0);
  aggregate<<<nb8, 256, 0, stream>>>(Cbuf, row_ofs, colidx, Hbuf, N);
  // fused head
  gemm_head<<<mb, 256, 0, stream>>>(Hbuf, Bht, cqh, Wh2, bh2, (float*)d_out, N, 256);
}